// Round 6
// baseline (1152.941 us; speedup 1.0000x reference)
//
#include <hip/hip_runtime.h>
#include <hip/hip_bf16.h>
#include <math.h>

typedef unsigned short u16;
typedef __bf16 bf16x8 __attribute__((ext_vector_type(8)));
typedef float floatx4 __attribute__((ext_vector_type(4)));

#define LORA_SCALING 2.0f   // alpha 32 / rank 16

// Frag-major layout for all GEMM operands (1 KB per 16x32 fragment):
// frag idx = (row/16)*(K/32) + (k/32); lane l holds row = 16*(row/16)+(l&15),
// k = 32*(k/32) + (l>>4)*8 .. +7, at frag*512 + l*8 (u16). One ds_read_b128 or
// global load at base + l*16 = one MFMA operand; DMA of a frag is a linear 1 KB.

// ---------- helpers ----------
__device__ __forceinline__ u16 f2bf(float f) {
  unsigned u = __float_as_uint(f);
  u += 0x7fffu + ((u >> 16) & 1u);   // round-to-nearest-even
  return (u16)(u >> 16);
}
__device__ __forceinline__ float bflo(unsigned u) { return __uint_as_float(u << 16); }
__device__ __forceinline__ float bfhi(unsigned u) { return __uint_as_float(u & 0xffff0000u); }

// ---------- zero amax slots + lora T buffers (ws poisoned 0xAA each launch) ----------
__global__ void zero_kernel(unsigned* amax, float* T1, float* T2, int n) {
  int i = blockIdx.x * blockDim.x + threadIdx.x;
  if (i < 2) amax[i] = 0u;
  int stride = gridDim.x * blockDim.x;
  for (int j = i; j < n; j += stride) { T1[j] = 0.f; T2[j] = 0.f; }
}

// ---------- fused absmax of both weight tensors ----------
__global__ void absmax2_kernel(const float* __restrict__ wa, const float* __restrict__ wb,
                               long long n4, unsigned* __restrict__ out) {
  int which = blockIdx.x & 1;
  const float* w = which ? wb : wa;
  long long i = (long long)(blockIdx.x >> 1) * blockDim.x + threadIdx.x;
  long long stride = (long long)(gridDim.x >> 1) * blockDim.x;
  float m = 0.f;
  for (; i < n4; i += stride) {
    float4 v = ((const float4*)w)[i];
    m = fmaxf(m, fmaxf(fmaxf(fabsf(v.x), fabsf(v.y)), fmaxf(fabsf(v.z), fabsf(v.w))));
  }
#pragma unroll
  for (int o = 32; o > 0; o >>= 1) m = fmaxf(m, __shfl_xor(m, o, 64));
  __shared__ float sm[4];
  int lane = threadIdx.x & 63, wv = threadIdx.x >> 6;
  if (lane == 0) sm[wv] = m;
  __syncthreads();
  if (threadIdx.x == 0) {
    float mm = fmaxf(fmaxf(sm[0], sm[1]), fmaxf(sm[2], sm[3]));
    atomicMax(out + which, __float_as_uint(mm));   // nonneg: uint order == float order
  }
}

// ---------- packing helpers ----------
__device__ __forceinline__ void pack_chunk_q(const float* __restrict__ w, u16* __restrict__ dst,
                                             long long c, int kc3, float inv, float scale) {
  long long m = c >> kc3;
  int k8 = (int)(c & ((1ll << kc3) - 1));
  long long frag = (m >> 4) * ((1ll << kc3) >> 2) + (k8 >> 2);
  long long d = frag * 64 + ((m & 15) | ((k8 & 3) << 4));
  const float4* s = (const float4*)(w + c * 8);
  float4 a = s[0], b = s[1];
  union { u16 h[8]; uint4 v; } o;
  o.h[0] = f2bf(fminf(fmaxf(rintf(a.x * inv), -128.f), 127.f) * scale);
  o.h[1] = f2bf(fminf(fmaxf(rintf(a.y * inv), -128.f), 127.f) * scale);
  o.h[2] = f2bf(fminf(fmaxf(rintf(a.z * inv), -128.f), 127.f) * scale);
  o.h[3] = f2bf(fminf(fmaxf(rintf(a.w * inv), -128.f), 127.f) * scale);
  o.h[4] = f2bf(fminf(fmaxf(rintf(b.x * inv), -128.f), 127.f) * scale);
  o.h[5] = f2bf(fminf(fmaxf(rintf(b.y * inv), -128.f), 127.f) * scale);
  o.h[6] = f2bf(fminf(fmaxf(rintf(b.z * inv), -128.f), 127.f) * scale);
  o.h[7] = f2bf(fminf(fmaxf(rintf(b.w * inv), -128.f), 127.f) * scale);
  ((uint4*)dst)[d] = o.v;
}
__device__ __forceinline__ void pack_chunk_c(const float* __restrict__ x, u16* __restrict__ dst,
                                             long long c, int kc3) {
  long long m = c >> kc3;
  int k8 = (int)(c & ((1ll << kc3) - 1));
  long long frag = (m >> 4) * ((1ll << kc3) >> 2) + (k8 >> 2);
  long long d = frag * 64 + ((m & 15) | ((k8 & 3) << 4));
  const float4* s = (const float4*)(x + c * 8);
  float4 a = s[0], b = s[1];
  union { u16 h[8]; uint4 v; } o;
  o.h[0] = f2bf(a.x); o.h[1] = f2bf(a.y); o.h[2] = f2bf(a.z); o.h[3] = f2bf(a.w);
  o.h[4] = f2bf(b.x); o.h[5] = f2bf(b.y); o.h[6] = f2bf(b.z); o.h[7] = f2bf(b.w);
  ((uint4*)dst)[d] = o.v;
}

// ---------- fused: quant-pack W_fc, quant-pack W_pr, convert-pack x ----------
__global__ void pack_all_kernel(const float* __restrict__ wfc, const float* __restrict__ wpr,
                                const float* __restrict__ x, const unsigned* __restrict__ amax,
                                u16* __restrict__ qfc, u16* __restrict__ qpr, u16* __restrict__ xb,
                                long long nfc, long long npr, long long nx, int kfc, int kpr, int kx) {
  float am0 = __uint_as_float(amax[0]);
  float am1 = __uint_as_float(amax[1]);
  float sc0 = am0 * (1.0f / 127.0f), in0 = 127.0f / am0;
  float sc1 = am1 * (1.0f / 127.0f), in1 = 127.0f / am1;
  long long i = (long long)blockIdx.x * blockDim.x + threadIdx.x;
  long long stride = (long long)gridDim.x * blockDim.x;
  long long tot = nfc + npr + nx;
  for (; i < tot; i += stride) {
    if (i < nfc)            pack_chunk_q(wfc, qfc, i, kfc, in0, sc0);
    else if (i < nfc + npr) pack_chunk_q(wpr, qpr, i - nfc, kpr, in1, sc1);
    else                    pack_chunk_c(x, xb, i - nfc - npr, kx);
  }
}

// ---------- LoRA t = X(packed bf16) @ A^T(fp32), rank 16, split-K + atomicAdd ----------
__global__ void lora_t_kernel(const u16* __restrict__ X, const float* __restrict__ A,
                              float* __restrict__ T, int K, int S) {
  int r = threadIdx.x & 15;
  int mi = threadIdx.x >> 4;
  long long row = (long long)blockIdx.x * 16 + mi;
  int nk = K >> 5;
  const u16* xp = X + ((row >> 4) * (long long)nk) * 512 + (row & 15) * 8;
  const float* ap = A + (long long)r * K;
  int kper = K / S;
  int k0 = blockIdx.y * kper, k1 = k0 + kper;
  float a0 = 0.f, a1 = 0.f, a2 = 0.f, a3 = 0.f;
  for (int k = k0; k < k1; k += 32) {
    long long base = (long long)(k >> 5) * 512;
    uint4 x0 = *(const uint4*)(xp + base);
    uint4 x1 = *(const uint4*)(xp + base + 128);
    uint4 x2 = *(const uint4*)(xp + base + 256);
    uint4 x3 = *(const uint4*)(xp + base + 384);
    const float4* f = (const float4*)(ap + k);
    float4 f0 = f[0], f1 = f[1], f2 = f[2], f3 = f[3], f4 = f[4], f5 = f[5], f6 = f[6], f7 = f[7];
    a0 += bflo(x0.x) * f0.x + bfhi(x0.x) * f0.y + bflo(x0.y) * f0.z + bfhi(x0.y) * f0.w
        + bflo(x0.z) * f1.x + bfhi(x0.z) * f1.y + bflo(x0.w) * f1.z + bfhi(x0.w) * f1.w;
    a1 += bflo(x1.x) * f2.x + bfhi(x1.x) * f2.y + bflo(x1.y) * f2.z + bfhi(x1.y) * f2.w
        + bflo(x1.z) * f3.x + bfhi(x1.z) * f3.y + bflo(x1.w) * f3.z + bfhi(x1.w) * f3.w;
    a2 += bflo(x2.x) * f4.x + bfhi(x2.x) * f4.y + bflo(x2.y) * f4.z + bfhi(x2.y) * f4.w
        + bflo(x2.z) * f5.x + bfhi(x2.z) * f5.y + bflo(x2.w) * f5.z + bfhi(x2.w) * f5.w;
    a3 += bflo(x3.x) * f6.x + bfhi(x3.x) * f6.y + bflo(x3.y) * f6.z + bfhi(x3.y) * f6.w
        + bflo(x3.z) * f7.x + bfhi(x3.z) * f7.y + bflo(x3.w) * f7.z + bfhi(x3.w) * f7.w;
  }
  atomicAdd(&T[row * 16 + r], (a0 + a1) + (a2 + a3));
}

// ---------- main GEMM (m97 structure): 128x128 tile, BK=32, 16 KB single-buffer LDS ----------
// 256 threads = 4 waves (2x2), each wave 4x4 frags of 16x16x32 bf16 MFMA.
// Per K-iter: 16 frag DMAs (4 per wave, each a linear 1 KB global_load_lds) ->
// __syncthreads -> 8 conflict-free ds_read_b128 per wave -> 16 MFMA -> __syncthreads.
template<int DO_GELU>
__global__ __launch_bounds__(256)
void gemm_qlora_kernel(const u16* __restrict__ Apk, const u16* __restrict__ Bpk,
                       const float* __restrict__ bias, const float* __restrict__ T,
                       const float* __restrict__ Bl, void* __restrict__ outp,
                       int M, int N, int K) {
  __shared__ u16 sA[8 * 512];   // 8 A-frags (8 KB)
  __shared__ u16 sB[8 * 512];   // 8 B-frags (8 KB)
  const int tid = threadIdx.x;
  const int wave = tid >> 6, lane = tid & 63;
  const int quad = lane >> 4, m16 = lane & 15;

  // XCD partition: id&7 = XCD, bm-local fastest within XCD (A strip L2-resident)
  const int per = (M >> 7) >> 3;
  int xcd = blockIdx.x & 7, t = blockIdx.x >> 3;
  int bm = xcd * per + (t & (per - 1));
  int bn = t / per;

  const int wm = (wave >> 1) * 64, wn = (wave & 1) * 64;
  const int nk = K >> 5;

  // per-wave staged frags: A rows {2*wave, 2*wave+1}, B rows {2*wave, 2*wave+1}
  const u16* gA0 = Apk + ((size_t)(bm * 8 + wave * 2) * nk) * 512 + lane * 8;
  const u16* gA1 = gA0 + (size_t)nk * 512;
  const u16* gB0 = Bpk + ((size_t)(bn * 8 + wave * 2) * nk) * 512 + lane * 8;
  const u16* gB1 = gB0 + (size_t)nk * 512;
  u16* lA0 = sA + (wave * 2) * 512;
  u16* lA1 = lA0 + 512;
  u16* lB0 = sB + (wave * 2) * 512;
  u16* lB1 = lB0 + 512;

  const u16* rA = sA + (wm >> 4) * 512 + lane * 8;   // this wave's 4 A-frag lanes
  const u16* rB = sB + (wn >> 4) * 512 + lane * 8;

  floatx4 acc[4][4] = {};

#pragma unroll 1
  for (int kt = 0; kt < nk; ++kt) {
    size_t o = (size_t)kt * 512;
    __builtin_amdgcn_global_load_lds((const __attribute__((address_space(1))) void*)(gA0 + o),
                                     (__attribute__((address_space(3))) void*)lA0, 16, 0, 0);
    __builtin_amdgcn_global_load_lds((const __attribute__((address_space(1))) void*)(gA1 + o),
                                     (__attribute__((address_space(3))) void*)lA1, 16, 0, 0);
    __builtin_amdgcn_global_load_lds((const __attribute__((address_space(1))) void*)(gB0 + o),
                                     (__attribute__((address_space(3))) void*)lB0, 16, 0, 0);
    __builtin_amdgcn_global_load_lds((const __attribute__((address_space(1))) void*)(gB1 + o),
                                     (__attribute__((address_space(3))) void*)lB1, 16, 0, 0);
    __syncthreads();

    bf16x8 av[4], bv[4];
#pragma unroll
    for (int mt = 0; mt < 4; ++mt) av[mt] = *(const bf16x8*)(rA + mt * 512);
#pragma unroll
    for (int nt = 0; nt < 4; ++nt) bv[nt] = *(const bf16x8*)(rB + nt * 512);
#pragma unroll
    for (int mt = 0; mt < 4; ++mt)
#pragma unroll
      for (int nt = 0; nt < 4; ++nt)
        acc[mt][nt] = __builtin_amdgcn_mfma_f32_16x16x32_bf16(av[mt], bv[nt], acc[mt][nt], 0, 0, 0);
    __syncthreads();
  }

  // epilogue: C/D layout row=(lane>>4)*4+reg, col=lane&15
  const float* Trow = T + (size_t)bm * 128 * 16;
  const float* Blrow = Bl + (size_t)bn * 128 * 16;
#pragma unroll
  for (int mt = 0; mt < 4; ++mt) {
#pragma unroll
    for (int r = 0; r < 4; ++r) {
      int ml = wm + mt * 16 + quad * 4 + r;
      size_t gm = (size_t)bm * 128 + ml;
      const float4* tv = (const float4*)(Trow + (size_t)ml * 16);
      float4 ta = tv[0], tb = tv[1], tc = tv[2], td = tv[3];
#pragma unroll
      for (int nt = 0; nt < 4; ++nt) {
        int nl = wn + nt * 16 + m16;
        size_t gn = (size_t)bn * 128 + nl;
        const float4* bv4 = (const float4*)(Blrow + (size_t)nl * 16);
        float4 ba = bv4[0], bb = bv4[1], bc = bv4[2], bd = bv4[3];
        float lora = ta.x * ba.x + ta.y * ba.y + ta.z * ba.z + ta.w * ba.w
                   + tb.x * bb.x + tb.y * bb.y + tb.z * bb.z + tb.w * bb.w
                   + tc.x * bc.x + tc.y * bc.y + tc.z * bc.z + tc.w * bc.w
                   + td.x * bd.x + td.y * bd.y + td.z * bd.z + td.w * bd.w;
        float v = acc[mt][nt][r] + bias[gn] + LORA_SCALING * lora;
        if (DO_GELU) {
          float g = 0.5f * v * (1.0f + erff(v * 0.70710678118654752f));
          // store into packed layout for the next GEMM's A operand ([M][N])
          size_t dst = ((gm >> 4) * (size_t)(N >> 5) + (gn >> 5)) * 512
                     + (gm & 15) * 8 + (((gn >> 3) & 3) << 7) + (gn & 7);
          ((u16*)outp)[dst] = f2bf(g);
        } else {
          ((float*)outp)[gm * (size_t)N + gn] = v;
        }
      }
    }
  }
}

// ---------- launch ----------
extern "C" void kernel_launch(void* const* d_in, const int* in_sizes, int n_in,
                              void* d_out, int out_size, void* d_ws, size_t ws_size,
                              hipStream_t stream) {
  const float* x    = (const float*)d_in[0];
  const float* W_fc = (const float*)d_in[1];
  const float* b_fc = (const float*)d_in[2];
  const float* A_fc = (const float*)d_in[3];
  const float* B_fc = (const float*)d_in[4];
  const float* W_pr = (const float*)d_in[5];
  const float* b_pr = (const float*)d_in[6];
  const float* A_pr = (const float*)d_in[7];
  const float* B_pr = (const float*)d_in[8];
  float* out = (float*)d_out;

  const int F = in_sizes[2];                 // 4096
  const int D = in_sizes[6];                 // 1024
  const int M = in_sizes[0] / D;             // 8192
  int dsh = 0; while ((1 << dsh) < D) ++dsh;
  int fsh = 0; while ((1 << fsh) < F) ++fsh;

  char* ws = (char*)d_ws;
  unsigned* amax = (unsigned*)ws;
  u16* wq_fc = (u16*)(ws + 1024);
  u16* wq_pr = wq_fc + (size_t)F * D;
  u16* xbf   = wq_pr + (size_t)D * F;
  u16* gbf   = xbf + (size_t)M * D;
  float* t1  = (float*)(gbf + (size_t)M * F);
  float* t2  = t1 + (size_t)M * 16;

  long long wfd4 = (long long)F * D / 4;
  long long wfd8 = (long long)F * D / 8;
  long long xch  = (long long)M * D / 8;

  zero_kernel<<<1024, 256, 0, stream>>>(amax, t1, t2, M * 16);
  absmax2_kernel<<<2048, 256, 0, stream>>>(W_fc, W_pr, wfd4, amax);
  pack_all_kernel<<<2048, 256, 0, stream>>>(W_fc, W_pr, x, amax, wq_fc, wq_pr, xbf,
                                            wfd8, wfd8, xch, dsh - 3, fsh - 3, dsh - 3);
  lora_t_kernel<<<dim3(M / 16, 2), 256, 0, stream>>>(xbf, A_fc, t1, D, 2);
  gemm_qlora_kernel<1><<<dim3((M / 128) * (F / 128)), 256, 0, stream>>>(
      xbf, wq_fc, b_fc, t1, B_fc, (void*)gbf, M, F, D);
  lora_t_kernel<<<dim3(M / 16, 4), 256, 0, stream>>>(gbf, A_pr, t2, F, 4);
  gemm_qlora_kernel<0><<<dim3((M / 128) * (D / 128)), 256, 0, stream>>>(
      gbf, wq_pr, b_pr, t2, B_pr, (void*)out, M, D, F);
}

// Round 7
// 759.408 us; speedup vs baseline: 1.5182x; 1.5182x over previous
//
#include <hip/hip_runtime.h>
#include <hip/hip_bf16.h>
#include <math.h>

typedef unsigned short u16;
typedef __bf16 bf16x8 __attribute__((ext_vector_type(8)));
typedef float floatx4 __attribute__((ext_vector_type(4)));

#define LORA_SCALING 2.0f   // alpha 32 / rank 16

// Frag-major layout for all GEMM operands (1 KB per 16x32 fragment):
// frag idx = (row/16)*(K/32) + (k/32); lane l holds row = 16*(row/16)+(l&15),
// k = 32*(k/32) + (l>>4)*8 .. +7, at frag*512 + l*8 (u16).
// One global_load_dwordx4 at base + l*16 = one MFMA operand, fully coalesced.

// ---------- helpers ----------
__device__ __forceinline__ u16 f2bf(float f) {
  unsigned u = __float_as_uint(f);
  u += 0x7fffu + ((u >> 16) & 1u);   // round-to-nearest-even
  return (u16)(u >> 16);
}
__device__ __forceinline__ float bflo(unsigned u) { return __uint_as_float(u << 16); }
__device__ __forceinline__ float bfhi(unsigned u) { return __uint_as_float(u & 0xffff0000u); }

// ---------- zero amax slots (ws poisoned 0xAA each launch) ----------
__global__ void zero_kernel(unsigned* amax) {
  if (threadIdx.x < 2) amax[threadIdx.x] = 0u;
}

// ---------- fused absmax of both weight tensors ----------
__global__ void absmax2_kernel(const float* __restrict__ wa, const float* __restrict__ wb,
                               long long n4, unsigned* __restrict__ out) {
  int which = blockIdx.x & 1;
  const float* w = which ? wb : wa;
  long long i = (long long)(blockIdx.x >> 1) * blockDim.x + threadIdx.x;
  long long stride = (long long)(gridDim.x >> 1) * blockDim.x;
  float m = 0.f;
  for (; i < n4; i += stride) {
    float4 v = ((const float4*)w)[i];
    m = fmaxf(m, fmaxf(fmaxf(fabsf(v.x), fabsf(v.y)), fmaxf(fabsf(v.z), fabsf(v.w))));
  }
#pragma unroll
  for (int o = 32; o > 0; o >>= 1) m = fmaxf(m, __shfl_xor(m, o, 64));
  __shared__ float sm[4];
  int lane = threadIdx.x & 63, wv = threadIdx.x >> 6;
  if (lane == 0) sm[wv] = m;
  __syncthreads();
  if (threadIdx.x == 0) {
    float mm = fmaxf(fmaxf(sm[0], sm[1]), fmaxf(sm[2], sm[3]));
    atomicMax(out + which, __float_as_uint(mm));   // nonneg: uint order == float order
  }
}

// ---------- packing, dst-major: coalesced 16B writes, gathered 32B reads ----------
// dst chunk d: lane-part l = d&63, frag = d>>6; row = (frag/nkc)*16 + (l&15),
// k8 = (frag%nkc)*4 + (l>>4); src = row*(K/8) + k8 (32B contiguous fp32).
__device__ __forceinline__ void pack_q(const float* __restrict__ w, u16* __restrict__ dst,
                                       long long d, int nkc, int kc3, float inv, float scale) {
  int l = (int)(d & 63);
  long long frag = d >> 6;
  long long m = (frag / nkc) * 16 + (l & 15);
  long long k8 = (frag % nkc) * 4 + (l >> 4);
  const float4* s = (const float4*)(w + ((m << kc3) + k8) * 8);
  float4 a = s[0], b = s[1];
  union { u16 h[8]; uint4 v; } o;
  o.h[0] = f2bf(fminf(fmaxf(rintf(a.x * inv), -128.f), 127.f) * scale);
  o.h[1] = f2bf(fminf(fmaxf(rintf(a.y * inv), -128.f), 127.f) * scale);
  o.h[2] = f2bf(fminf(fmaxf(rintf(a.z * inv), -128.f), 127.f) * scale);
  o.h[3] = f2bf(fminf(fmaxf(rintf(a.w * inv), -128.f), 127.f) * scale);
  o.h[4] = f2bf(fminf(fmaxf(rintf(b.x * inv), -128.f), 127.f) * scale);
  o.h[5] = f2bf(fminf(fmaxf(rintf(b.y * inv), -128.f), 127.f) * scale);
  o.h[6] = f2bf(fminf(fmaxf(rintf(b.z * inv), -128.f), 127.f) * scale);
  o.h[7] = f2bf(fminf(fmaxf(rintf(b.w * inv), -128.f), 127.f) * scale);
  ((uint4*)dst)[d] = o.v;
}
__device__ __forceinline__ void pack_c(const float* __restrict__ x, u16* __restrict__ dst,
                                       long long d, int nkc, int kc3) {
  int l = (int)(d & 63);
  long long frag = d >> 6;
  long long m = (frag / nkc) * 16 + (l & 15);
  long long k8 = (frag % nkc) * 4 + (l >> 4);
  const float4* s = (const float4*)(x + ((m << kc3) + k8) * 8);
  float4 a = s[0], b = s[1];
  union { u16 h[8]; uint4 v; } o;
  o.h[0] = f2bf(a.x); o.h[1] = f2bf(a.y); o.h[2] = f2bf(a.z); o.h[3] = f2bf(a.w);
  o.h[4] = f2bf(b.x); o.h[5] = f2bf(b.y); o.h[6] = f2bf(b.z); o.h[7] = f2bf(b.w);
  ((uint4*)dst)[d] = o.v;
}

__global__ void pack_all_kernel(const float* __restrict__ wfc, const float* __restrict__ wpr,
                                const float* __restrict__ x, const unsigned* __restrict__ amax,
                                u16* __restrict__ qfc, u16* __restrict__ qpr, u16* __restrict__ xb,
                                long long nfc, long long npr, long long nx, int kfc, int kpr, int kx) {
  float am0 = __uint_as_float(amax[0]);
  float am1 = __uint_as_float(amax[1]);
  float sc0 = am0 * (1.0f / 127.0f), in0 = 127.0f / am0;
  float sc1 = am1 * (1.0f / 127.0f), in1 = 127.0f / am1;
  long long i = (long long)blockIdx.x * blockDim.x + threadIdx.x;
  long long stride = (long long)gridDim.x * blockDim.x;
  long long tot = nfc + npr + nx;
  for (; i < tot; i += stride) {
    if (i < nfc)            pack_q(wfc, qfc, i, 1 << (kfc - 2), kfc, in0, sc0);
    else if (i < nfc + npr) pack_q(wpr, qpr, i - nfc, 1 << (kpr - 2), kpr, in1, sc1);
    else                    pack_c(x, xb, i - nfc - npr, 1 << (kx - 2), kx);
  }
}

// ---------- LoRA t = X(packed bf16) @ A^T(fp32): one wave per row, X read once ----------
__global__ void lora_t_kernel(const u16* __restrict__ X, const float* __restrict__ A,
                              float* __restrict__ T, int K) {
  int wv = threadIdx.x >> 6, lane = threadIdx.x & 63;
  long long row = (long long)blockIdx.x * 4 + wv;
  int nk = K >> 5;
  const u16* xp = X + ((row >> 4) * (long long)nk) * 512 + (row & 15) * 8;
  float acc[16];
#pragma unroll
  for (int r = 0; r < 16; ++r) acc[r] = 0.f;
  int nseg = K >> 3;
  for (int seg = lane; seg < nseg; seg += 64) {
    uint4 xv = *(const uint4*)(xp + (seg >> 2) * 512 + (seg & 3) * 128);
    float x0 = bflo(xv.x), x1 = bfhi(xv.x), x2 = bflo(xv.y), x3 = bfhi(xv.y);
    float x4 = bflo(xv.z), x5 = bfhi(xv.z), x6 = bflo(xv.w), x7 = bfhi(xv.w);
    int k = seg * 8;
#pragma unroll
    for (int r = 0; r < 16; ++r) {
      const float4* ar = (const float4*)(A + (long long)r * K + k);
      float4 a0 = ar[0], a1 = ar[1];
      acc[r] += x0 * a0.x + x1 * a0.y + x2 * a0.z + x3 * a0.w
              + x4 * a1.x + x5 * a1.y + x6 * a1.z + x7 * a1.w;
    }
  }
#pragma unroll
  for (int r = 0; r < 16; ++r) {
    float v = acc[r];
#pragma unroll
    for (int o = 32; o > 0; o >>= 1) v += __shfl_xor(v, o, 64);
    if (lane == r) T[row * 16 + r] = v;
  }
}

// ---------- main GEMM: no LDS/barriers; frag-major direct loads, reg ping-pong ----------
// 128x128 block, 256 threads = 4 waves (2x2), each wave 64x64 = 4x4 frags of 16x16x32 bf16.
// __launch_bounds__(256,2): ~256-reg budget so both ping-pong arrays stay live
// (r5's (256,3) capped VGPR=84 -> compiler sank loads -> latency-bound).
template<int DO_GELU>
__global__ __launch_bounds__(256, 2)
void gemm_qlora_kernel(const u16* __restrict__ Apk, const u16* __restrict__ Bpk,
                       const float* __restrict__ bias, const float* __restrict__ T,
                       const float* __restrict__ Bl, void* __restrict__ outp,
                       int M, int N, int K) {
  const int tid = threadIdx.x;
  const int wave = tid >> 6, lane = tid & 63;
  const int quad = lane >> 4, m16 = lane & 15;

  const int per = (M >> 7) >> 3;          // bm tiles per XCD
  int j = blockIdx.x & 7, t = blockIdx.x >> 3;
  int bm = j * per + (t & (per - 1));
  int bn = t / per;

  const int wm = (wave >> 1) * 64, wn = (wave & 1) * 64;
  const int nk = K >> 5;
  const size_t ms = (size_t)nk * 512;     // frag-row stride (u16)

  const u16* Ab = Apk + (size_t)(bm * 8 + (wm >> 4)) * ms + lane * 8;
  const u16* Bb = Bpk + (size_t)(bn * 8 + (wn >> 4)) * ms + lane * 8;

  floatx4 acc[4][4] = {};
  bf16x8 a0[4], b0[4], a1[4], b1[4];

#pragma unroll
  for (int i = 0; i < 4; ++i) {
    a0[i] = *(const bf16x8*)(Ab + i * ms);
    b0[i] = *(const bf16x8*)(Bb + i * ms);
  }

#pragma unroll 1
  for (int kt = 0; kt < nk; kt += 2) {
    const u16* An = Ab + (size_t)(kt + 1) * 512;
    const u16* Bn = Bb + (size_t)(kt + 1) * 512;
#pragma unroll
    for (int i = 0; i < 4; ++i) {
      a1[i] = *(const bf16x8*)(An + i * ms);
      b1[i] = *(const bf16x8*)(Bn + i * ms);
    }
#pragma unroll
    for (int mt = 0; mt < 4; ++mt)
#pragma unroll
      for (int nt = 0; nt < 4; ++nt)
        acc[mt][nt] = __builtin_amdgcn_mfma_f32_16x16x32_bf16(a0[mt], b0[nt], acc[mt][nt], 0, 0, 0);
    const u16* An2 = Ab + (size_t)(kt + 2) * 512;   // may overrun into pad (values unused)
    const u16* Bn2 = Bb + (size_t)(kt + 2) * 512;
#pragma unroll
    for (int i = 0; i < 4; ++i) {
      a0[i] = *(const bf16x8*)(An2 + i * ms);
      b0[i] = *(const bf16x8*)(Bn2 + i * ms);
    }
#pragma unroll
    for (int mt = 0; mt < 4; ++mt)
#pragma unroll
      for (int nt = 0; nt < 4; ++nt)
        acc[mt][nt] = __builtin_amdgcn_mfma_f32_16x16x32_bf16(a1[mt], b1[nt], acc[mt][nt], 0, 0, 0);
  }

  // epilogue: C/D layout row=(lane>>4)*4+reg, col=lane&15
  const float* Trow = T + (size_t)bm * 128 * 16;
  const float* Blrow = Bl + (size_t)bn * 128 * 16;
#pragma unroll
  for (int mt = 0; mt < 4; ++mt) {
#pragma unroll
    for (int r = 0; r < 4; ++r) {
      int ml = wm + mt * 16 + quad * 4 + r;
      size_t gm = (size_t)bm * 128 + ml;
      const float4* tv = (const float4*)(Trow + (size_t)ml * 16);
      float4 ta = tv[0], tb = tv[1], tc = tv[2], td = tv[3];
#pragma unroll
      for (int nt = 0; nt < 4; ++nt) {
        int nl = wn + nt * 16 + m16;
        size_t gn = (size_t)bn * 128 + nl;
        const float4* bv4 = (const float4*)(Blrow + (size_t)nl * 16);
        float4 ba = bv4[0], bb = bv4[1], bc = bv4[2], bd = bv4[3];
        float lora = ta.x * ba.x + ta.y * ba.y + ta.z * ba.z + ta.w * ba.w
                   + tb.x * bb.x + tb.y * bb.y + tb.z * bb.z + tb.w * bb.w
                   + tc.x * bc.x + tc.y * bc.y + tc.z * bc.z + tc.w * bc.w
                   + td.x * bd.x + td.y * bd.y + td.z * bd.z + td.w * bd.w;
        float v = acc[mt][nt][r] + bias[gn] + LORA_SCALING * lora;
        if (DO_GELU) {
          float g = 0.5f * v * (1.0f + erff(v * 0.70710678118654752f));
          size_t dst = ((gm >> 4) * (size_t)(N >> 5) + (gn >> 5)) * 512
                     + (gm & 15) * 8 + (((gn >> 3) & 3) << 7) + (gn & 7);
          ((u16*)outp)[dst] = f2bf(g);
        } else {
          ((float*)outp)[gm * (size_t)N + gn] = v;
        }
      }
    }
  }
}

// ---------- launch ----------
extern "C" void kernel_launch(void* const* d_in, const int* in_sizes, int n_in,
                              void* d_out, int out_size, void* d_ws, size_t ws_size,
                              hipStream_t stream) {
  const float* x    = (const float*)d_in[0];
  const float* W_fc = (const float*)d_in[1];
  const float* b_fc = (const float*)d_in[2];
  const float* A_fc = (const float*)d_in[3];
  const float* B_fc = (const float*)d_in[4];
  const float* W_pr = (const float*)d_in[5];
  const float* b_pr = (const float*)d_in[6];
  const float* A_pr = (const float*)d_in[7];
  const float* B_pr = (const float*)d_in[8];
  float* out = (float*)d_out;

  const int F = in_sizes[2];                 // 4096
  const int D = in_sizes[6];                 // 1024
  const int M = in_sizes[0] / D;             // 8192
  int dsh = 0; while ((1 << dsh) < D) ++dsh;
  int fsh = 0; while ((1 << fsh) < F) ++fsh;

  const size_t PAD = 1 << 17;                // 256 KB pad per packed buf (prefetch overrun)
  char* ws = (char*)d_ws;
  unsigned* amax = (unsigned*)ws;
  u16* wq_fc = (u16*)(ws + 1024);
  u16* wq_pr = wq_fc + (size_t)F * D + PAD;
  u16* xbf   = wq_pr + (size_t)D * F + PAD;
  u16* gbf   = xbf + (size_t)M * D + PAD;
  float* t1  = (float*)(gbf + (size_t)M * F + PAD);
  float* t2  = t1 + (size_t)M * 16;

  long long wfd4 = (long long)F * D / 4;
  long long wfd8 = (long long)F * D / 8;
  long long xch  = (long long)M * D / 8;

  zero_kernel<<<1, 64, 0, stream>>>(amax);
  absmax2_kernel<<<2048, 256, 0, stream>>>(W_fc, W_pr, wfd4, amax);
  pack_all_kernel<<<2048, 256, 0, stream>>>(W_fc, W_pr, x, amax, wq_fc, wq_pr, xbf,
                                            wfd8, wfd8, xch, dsh - 3, fsh - 3, dsh - 3);
  lora_t_kernel<<<M / 4, 256, 0, stream>>>(xbf, A_fc, t1, D);
  gemm_qlora_kernel<1><<<dim3((M / 128) * (F / 128)), 256, 0, stream>>>(
      xbf, wq_fc, b_fc, t1, B_fc, (void*)gbf, M, F, D);
  lora_t_kernel<<<M / 4, 256, 0, stream>>>(gbf, A_pr, t2, F);
  gemm_qlora_kernel<0><<<dim3((M / 128) * (D / 128)), 256, 0, stream>>>(
      gbf, wq_pr, b_pr, t2, B_pr, (void*)out, M, D, F);
}